// Round 6
// baseline (288.333 us; speedup 1.0000x reference)
//
#include <hip/hip_runtime.h>
#include <hip/hip_bf16.h>

#define B_ 4
#define S_ 1024
#define D_ 256
#define H_ 8
#define LRELU_ALPHA 0.2f
#define MAXDEG 128

typedef __attribute__((ext_vector_type(8))) short short8;
typedef __attribute__((ext_vector_type(4))) float floatx4;

__device__ __forceinline__ float bf2f(unsigned short u) {
    union { unsigned int i; float f; } c; c.i = ((unsigned int)u) << 16; return c.f;
}
__device__ __forceinline__ unsigned short f2bf(float f) {
    union { float f; unsigned int u; } c; c.f = f;
    unsigned int r = (c.u + 0x7FFF + ((c.u >> 16) & 1)) >> 16;
    return (unsigned short)r;
}

// ---------------- CSR build ----------------
__global__ __launch_bounds__(1024) void k_csr(const float* __restrict__ adj,
        int* __restrict__ nbr, int* __restrict__ cnt) {
    int row = blockIdx.x;
    int j = threadIdx.x;
    __shared__ int c;
    if (j == 0) c = 0;
    __syncthreads();
    float a = adj[(size_t)row * S_ + j];
    if (a > 0.f) {
        int s = atomicAdd(&c, 1);
        if (s < MAXDEG) nbr[row * MAXDEG + s] = j;
    }
    __syncthreads();
    if (j == 0) cnt[row] = c < MAXDEG ? c : MAXDEG;
}

// ---------------- fp32 -> bf16 ----------------
__global__ void k_cast4(const float* __restrict__ x, unsigned short* __restrict__ o, int n4) {
    int i = blockIdx.x * blockDim.x + threadIdx.x;
    if (i >= n4) return;
    float4 v = ((const float4*)x)[i];
    ushort4 u; u.x = f2bf(v.x); u.y = f2bf(v.y); u.z = f2bf(v.z); u.w = f2bf(v.w);
    ((ushort4*)o)[i] = u;
}

// ---------------- W[K][N] fp32 -> Bt[N][K] bf16 ----------------
__global__ __launch_bounds__(256) void k_castT(const float* __restrict__ W,
        unsigned short* __restrict__ out, int K, int N) {
    __shared__ float t[32][33];
    int k0 = blockIdx.x * 32, n0 = blockIdx.y * 32;
    int tx = threadIdx.x & 31, ty = threadIdx.x >> 5;
#pragma unroll
    for (int i = 0; i < 4; ++i)
        t[ty + 8 * i][tx] = W[(size_t)(k0 + ty + 8 * i) * N + n0 + tx];
    __syncthreads();
#pragma unroll
    for (int i = 0; i < 4; ++i)
        out[(size_t)(n0 + ty + 8 * i) * K + k0 + tx] = f2bf(t[tx][ty + 8 * i]);
}

// --- W2[256 k][2048 (h*256+d)] -> Bt2[256 d][2048 (h*256+k)] bf16 (per-head transpose) ---
__global__ __launch_bounds__(256) void k_castT2(const float* __restrict__ W2,
        unsigned short* __restrict__ out) {
    __shared__ float t[32][33];
    int k0 = blockIdx.x * 32, d0 = blockIdx.y * 32, h = blockIdx.z;
    int tx = threadIdx.x & 31, ty = threadIdx.x >> 5;
#pragma unroll
    for (int i = 0; i < 4; ++i)
        t[ty + 8 * i][tx] = W2[(size_t)(k0 + ty + 8 * i) * 2048 + h * 256 + d0 + tx];
    __syncthreads();
#pragma unroll
    for (int i = 0; i < 4; ++i)
        out[(size_t)(d0 + ty + 8 * i) * 2048 + h * 256 + k0 + tx] = f2bf(t[tx][ty + 8 * i]);
}

// --- w_s2[h][k] = sum_d W2[k][h*256+d]*as2[h][d]; likewise w_d2 ---
__global__ __launch_bounds__(256) void k_wvec2(const float* __restrict__ W2,
        const float* __restrict__ as2, const float* __restrict__ ad2,
        float* __restrict__ WS2, float* __restrict__ WD2) {
    int h = blockIdx.x, k = threadIdx.x;
    const float* wrow = W2 + (size_t)k * 2048 + h * 256;
    float s = 0.f, d = 0.f;
    for (int dd = 0; dd < 256; ++dd) {
        float w = wrow[dd];
        s += w * as2[h * 256 + dd];
        d += w * ad2[h * 256 + dd];
    }
    WS2[h * 256 + k] = s;
    WD2[h * 256 + k] = d;
}

// ---------------- MFMA GEMM: C[M,N] = A[M,K]bf16 @ Bt[N,K]bf16 ----------------
// modes: 0 f32 | 1 bf16 | 2 bf16 gelu(acc+bias) | 3 f32 acc+res+bias | 4 f32 acc+res
__global__ __launch_bounds__(256) void k_gemm_mfma(const unsigned short* __restrict__ A,
        const unsigned short* __restrict__ Bt, void* __restrict__ Cout,
        const float* __restrict__ bias, const float* __restrict__ res,
        int M, int N, int K, int mode) {
    __shared__ unsigned short As[64][40];
    __shared__ unsigned short Bs[64][40];
    int tid = threadIdx.x;
    int bm = blockIdx.y * 64, bn = blockIdx.x * 64;
    int lane = tid & 63, wv = tid >> 6;
    int wm = (wv & 1) * 32, wn = (wv >> 1) * 32;
    int lrow = lane & 15, lq = lane >> 4;
    floatx4 acc00 = {0.f,0.f,0.f,0.f}, acc01 = acc00, acc10 = acc00, acc11 = acc00;
    int sm = tid >> 2, skq = (tid & 3) * 8;
    for (int k0 = 0; k0 < K; k0 += 32) {
        *(short8*)&As[sm][skq] = *(const short8*)(A + (size_t)(bm + sm) * K + k0 + skq);
        *(short8*)&Bs[sm][skq] = *(const short8*)(Bt + (size_t)(bn + sm) * K + k0 + skq);
        __syncthreads();
        short8 a0 = *(const short8*)&As[wm + lrow][lq * 8];
        short8 a1 = *(const short8*)&As[wm + 16 + lrow][lq * 8];
        short8 b0 = *(const short8*)&Bs[wn + lrow][lq * 8];
        short8 b1 = *(const short8*)&Bs[wn + 16 + lrow][lq * 8];
        acc00 = __builtin_amdgcn_mfma_f32_16x16x32_bf16(a0, b0, acc00, 0, 0, 0);
        acc01 = __builtin_amdgcn_mfma_f32_16x16x32_bf16(a0, b1, acc01, 0, 0, 0);
        acc10 = __builtin_amdgcn_mfma_f32_16x16x32_bf16(a1, b0, acc10, 0, 0, 0);
        acc11 = __builtin_amdgcn_mfma_f32_16x16x32_bf16(a1, b1, acc11, 0, 0, 0);
        __syncthreads();
    }
#pragma unroll
    for (int mi = 0; mi < 2; ++mi)
#pragma unroll
        for (int ni = 0; ni < 2; ++ni) {
            floatx4 a = mi == 0 ? (ni == 0 ? acc00 : acc01) : (ni == 0 ? acc10 : acc11);
#pragma unroll
            for (int r = 0; r < 4; ++r) {
                int grow = bm + wm + mi * 16 + lq * 4 + r;
                int gcol = bn + wn + ni * 16 + lrow;
                size_t off = (size_t)grow * N + gcol;
                float v = a[r];
                if (mode == 0) ((float*)Cout)[off] = v;
                else if (mode == 1) ((unsigned short*)Cout)[off] = f2bf(v);
                else if (mode == 2) {
                    float x = v + bias[gcol];
                    float t = tanhf(0.7978845608028654f * (x + 0.044715f * x * x * x));
                    ((unsigned short*)Cout)[off] = f2bf(0.5f * x * (1.f + t));
                } else if (mode == 3) ((float*)Cout)[off] = v + res[off] + bias[gcol];
                else ((float*)Cout)[off] = v + res[off];
            }
        }
}

// ---------------- scores from bf16 hp (layers 0/1, dh=32) ----------------
__global__ __launch_bounds__(256) void k_scores(const unsigned short* __restrict__ hp,
        const float* __restrict__ asrc, const float* __restrict__ adst,
        float* __restrict__ src, float* __restrict__ dst, int dh) {
    int w = blockIdx.x * 4 + (threadIdx.x >> 6);
    int lane = threadIdx.x & 63;
    int h = w & (H_ - 1);
    int bs = w >> 3;
    const unsigned short* v = hp + (size_t)bs * H_ * dh + (size_t)h * dh;
    float s = 0.f, d = 0.f;
    for (int k = lane; k < dh; k += 64) {
        float x = bf2f(v[k]);
        s += x * asrc[h * dh + k];
        d += x * adst[h * dh + k];
    }
    for (int o = 32; o; o >>= 1) { s += __shfl_xor(s, o); d += __shfl_xor(d, o); }
    if (lane == 0) { src[w] = s; dst[w] = d; }
}

// ---------------- layer-2 scores straight from fp32 H via WS2/WD2 ----------------
__global__ __launch_bounds__(256) void k_scores2H(const float* __restrict__ H,
        const float* __restrict__ WS2, const float* __restrict__ WD2,
        float* __restrict__ src, float* __restrict__ dst) {
    int row = blockIdx.x * 4 + (threadIdx.x >> 6);
    int lane = threadIdx.x & 63;
    float4 v = ((const float4*)(H + (size_t)row * 256))[lane];
#pragma unroll
    for (int h = 0; h < 8; ++h) {
        float4 ws = ((const float4*)(WS2 + h * 256))[lane];
        float4 wd = ((const float4*)(WD2 + h * 256))[lane];
        float s = v.x * ws.x + v.y * ws.y + v.z * ws.z + v.w * ws.w;
        float d = v.x * wd.x + v.y * wd.y + v.z * wd.z + v.w * wd.w;
        for (int o = 32; o; o >>= 1) { s += __shfl_xor(s, o); d += __shfl_xor(d, o); }
        if (lane == 0) { src[row * 8 + h] = s; dst[row * 8 + h] = d; }
    }
}

// ------- attn layers 0/1 fused: out = elu(agg + X), fp32 + bf16 copies -------
__global__ __launch_bounds__(256) void k_attn_small_f(const unsigned short* __restrict__ hp,
        const float* __restrict__ src, const float* __restrict__ dst,
        const int* __restrict__ nbr, const int* __restrict__ cnts,
        const float* __restrict__ X, float* __restrict__ Hout,
        unsigned short* __restrict__ Hb) {
    int row = blockIdx.x;
    int tid = threadIdx.x;
    int rb = row & ~(S_ - 1);
    __shared__ int nb[MAXDEG];
    __shared__ float ss[8];
    __shared__ float ew[MAXDEG * 9];
    int cnt = cnts[row];
    for (int t = tid; t < cnt; t += 256) nb[t] = nbr[row * MAXDEG + t];
    if (tid < 8) ss[tid] = src[row * H_ + tid];
    __syncthreads();
    for (int idx = tid; idx < cnt * 8; idx += 256) {
        int n = idx >> 3, h = idx & 7;
        int j = nb[n];
        float e = ss[h] + dst[(rb + j) * H_ + h];
        ew[n * 9 + h] = e > 0.f ? e : LRELU_ALPHA * e;
    }
    __syncthreads();
    {
        int lane = tid & 63, wv = tid >> 6;
        int h = wv * 2 + (lane >> 5), sub = lane & 31;
        float m = -1e30f;
        for (int n = sub; n < cnt; n += 32) m = fmaxf(m, ew[n * 9 + h]);
        for (int o = 16; o; o >>= 1) m = fmaxf(m, __shfl_xor(m, o));
        float s = 0.f;
        for (int n = sub; n < cnt; n += 32) {
            float v = __expf(ew[n * 9 + h] - m); ew[n * 9 + h] = v; s += v;
        }
        for (int o = 16; o; o >>= 1) s += __shfl_xor(s, o);
        float inv = s > 0.f ? 1.f / s : 0.f;
        for (int n = sub; n < cnt; n += 32) ew[n * 9 + h] *= inv;
    }
    __syncthreads();
    int h = tid >> 5;
    float acc0 = 0.f, acc1 = 0.f;
    const unsigned short* hpb = hp + (size_t)rb * 256;
    int n = 0;
    for (; n + 1 < cnt; n += 2) {
        int j0 = nb[n], j1 = nb[n + 1];
        float w0 = ew[n * 9 + h], w1 = ew[(n + 1) * 9 + h];
        acc0 += w0 * bf2f(hpb[(size_t)j0 * 256 + tid]);
        acc1 += w1 * bf2f(hpb[(size_t)j1 * 256 + tid]);
    }
    if (n < cnt) acc0 += ew[n * 9 + h] * bf2f(hpb[(size_t)nb[n] * 256 + tid]);
    float o = acc0 + acc1 + X[(size_t)row * 256 + tid];
    o = o > 0.f ? o : (__expf(o) - 1.f);
    Hout[(size_t)row * 256 + tid] = o;
    Hb[(size_t)row * 256 + tid] = f2bf(o);
}

// ------- layer-2 aggregation over H rows: Ycat[row][h*256+k] = (attn_h/8 @ H)[k] -------
__global__ __launch_bounds__(256) void k_attn_Y(const unsigned short* __restrict__ Hb,
        const float* __restrict__ src2, const float* __restrict__ dst2,
        const int* __restrict__ nbr, const int* __restrict__ cnts,
        unsigned short* __restrict__ Ycat) {
    int row = blockIdx.x;
    int tid = threadIdx.x;
    int rb = row & ~(S_ - 1);
    __shared__ int nb[MAXDEG];
    __shared__ float ss[8];
    __shared__ float ew[MAXDEG * 10];   // pitch 10: b64-aligned pairs, 2-way-bank-free
    int cnt = cnts[row];
    for (int t = tid; t < cnt; t += 256) nb[t] = nbr[row * MAXDEG + t];
    if (tid < 8) ss[tid] = src2[row * H_ + tid];
    __syncthreads();
    for (int idx = tid; idx < cnt * 8; idx += 256) {
        int n = idx >> 3, h = idx & 7;
        int j = nb[n];
        float e = ss[h] + dst2[(rb + j) * H_ + h];
        ew[n * 10 + h] = e > 0.f ? e : LRELU_ALPHA * e;
    }
    __syncthreads();
    {
        int lane = tid & 63, wv = tid >> 6;
        int h = wv * 2 + (lane >> 5), sub = lane & 31;
        float m = -1e30f;
        for (int n = sub; n < cnt; n += 32) m = fmaxf(m, ew[n * 10 + h]);
        for (int o = 16; o; o >>= 1) m = fmaxf(m, __shfl_xor(m, o));
        float s = 0.f;
        for (int n = sub; n < cnt; n += 32) {
            float v = __expf(ew[n * 10 + h] - m); ew[n * 10 + h] = v; s += v;
        }
        for (int o = 16; o; o >>= 1) s += __shfl_xor(s, o);
        float inv = s > 0.f ? 0.125f / s : 0.f;   // fold 1/H head-mean
        for (int n = sub; n < cnt; n += 32) ew[n * 10 + h] *= inv;
    }
    __syncthreads();
    float acc[8] = {0.f,0.f,0.f,0.f,0.f,0.f,0.f,0.f};
    for (int n = 0; n < cnt; ++n) {
        int j = nb[n];
        float v = bf2f(Hb[(size_t)(rb + j) * 256 + tid]);
        const float2* w = (const float2*)&ew[n * 10];
        float2 w01 = w[0], w23 = w[1], w45 = w[2], w67 = w[3];
        acc[0] += w01.x * v; acc[1] += w01.y * v;
        acc[2] += w23.x * v; acc[3] += w23.y * v;
        acc[4] += w45.x * v; acc[5] += w45.y * v;
        acc[6] += w67.x * v; acc[7] += w67.y * v;
    }
#pragma unroll
    for (int h = 0; h < 8; ++h)
        Ycat[(size_t)row * 2048 + h * 256 + tid] = f2bf(acc[h]);
}

// ---------------- LayerNorm (input G already has residual), fp32 + bf16 out ----------------
__global__ __launch_bounds__(256) void k_ln(const float* __restrict__ G,
        const float* __restrict__ g, const float* __restrict__ bta,
        float* __restrict__ HLN, unsigned short* __restrict__ HLNb) {
    int row = blockIdx.x * 4 + (threadIdx.x >> 6);
    int lane = threadIdx.x & 63;
    float4 v = ((const float4*)(G + (size_t)row * 256))[lane];
    float s = v.x + v.y + v.z + v.w;
    float q = v.x * v.x + v.y * v.y + v.z * v.z + v.w * v.w;
    for (int o = 32; o; o >>= 1) { s += __shfl_xor(s, o); q += __shfl_xor(q, o); }
    float mu = s * (1.f / 256.f);
    float var = q * (1.f / 256.f) - mu * mu;
    if (var < 0.f) var = 0.f;
    float rs = rsqrtf(var + 1e-5f);
    float4 gg = ((const float4*)g)[lane];
    float4 bb = ((const float4*)bta)[lane];
    float4 o;
    o.x = (v.x - mu) * rs * gg.x + bb.x;
    o.y = (v.y - mu) * rs * gg.y + bb.y;
    o.z = (v.z - mu) * rs * gg.z + bb.z;
    o.w = (v.w - mu) * rs * gg.w + bb.w;
    ((float4*)(HLN + (size_t)row * 256))[lane] = o;
    ushort4 ob; ob.x = f2bf(o.x); ob.y = f2bf(o.y); ob.z = f2bf(o.z); ob.w = f2bf(o.w);
    ((ushort4*)(HLNb + (size_t)row * 256))[lane] = ob;
}

extern "C" void kernel_launch(void* const* d_in, const int* in_sizes, int n_in,
                              void* d_out, int out_size, void* d_ws, size_t ws_size,
                              hipStream_t stream) {
    const float* adj   = (const float*)d_in[0];
    const float* x     = (const float*)d_in[1];
    const float* W0    = (const float*)d_in[2];
    const float* as0   = (const float*)d_in[3];
    const float* ad0   = (const float*)d_in[4];
    const float* W1    = (const float*)d_in[5];
    const float* as1   = (const float*)d_in[6];
    const float* ad1   = (const float*)d_in[7];
    const float* W2    = (const float*)d_in[8];
    const float* as2   = (const float*)d_in[9];
    const float* ad2   = (const float*)d_in[10];
    const float* ln_g  = (const float*)d_in[11];
    const float* ln_b  = (const float*)d_in[12];
    const float* ff_w1 = (const float*)d_in[13];
    const float* ff_b1 = (const float*)d_in[14];
    const float* ff_w2 = (const float*)d_in[15];
    const float* ff_b2 = (const float*)d_in[16];

    float* ws = (float*)d_ws;
    float* H    = ws;                          // [4096,256] f32
    float* G    = ws + 1048576;                // [4096,256] f32 (Y-GEMM out + residual)
    float* HLN  = ws + 2097152;                // [4096,256] f32
    unsigned short* Ycat = (unsigned short*)(ws + 3145728);   // [4096,2048] bf16
    unsigned short* HPb  = (unsigned short*)(ws + 7340032);   // [4096,256] bf16
    unsigned short* xb   = (unsigned short*)(ws + 7864320);
    unsigned short* Hb   = (unsigned short*)(ws + 8388608);
    unsigned short* HLNb = (unsigned short*)(ws + 8912896);
    unsigned short* MIDb = (unsigned short*)(ws + 9437184);   // [4096,512] bf16
    unsigned short* W0t  = (unsigned short*)(ws + 10485760);  // [256,256]
    unsigned short* W1t  = (unsigned short*)(ws + 10518528);
    unsigned short* W2t  = (unsigned short*)(ws + 10551296);  // [256,2048]
    unsigned short* F1t  = (unsigned short*)(ws + 10813440);  // [512,256]
    unsigned short* F2t  = (unsigned short*)(ws + 10878976);  // [256,512]
    float* WS2 = ws + 10944512;                // [8,256]
    float* WD2 = ws + 10946560;                // [8,256]
    float* SRC = ws + 10948608;                // [4096,8]
    float* DST = ws + 10981376;
    int*   NBR = (int*)(ws + 11014144);        // [4096,128]
    int*   CNT = (int*)(ws + 11538432);

    k_csr<<<4096, 1024, 0, stream>>>(adj, NBR, CNT);
    k_cast4<<<1024, 256, 0, stream>>>(x, xb, 262144);
    k_castT<<<dim3(8, 8),  256, 0, stream>>>(W0, W0t, 256, 256);
    k_castT<<<dim3(8, 8),  256, 0, stream>>>(W1, W1t, 256, 256);
    k_castT2<<<dim3(8, 8, 8), 256, 0, stream>>>(W2, W2t);
    k_castT<<<dim3(8, 16), 256, 0, stream>>>(ff_w1, F1t, 256, 512);
    k_castT<<<dim3(16, 8), 256, 0, stream>>>(ff_w2, F2t, 512, 256);
    k_wvec2<<<8, 256, 0, stream>>>(W2, as2, ad2, WS2, WD2);

    // ---- GAT layer 0 ----
    k_gemm_mfma<<<dim3(4, 64), 256, 0, stream>>>(xb, W0t, HPb, nullptr, nullptr, 4096, 256, 256, 1);
    k_scores<<<8192, 256, 0, stream>>>(HPb, as0, ad0, SRC, DST, 32);
    k_attn_small_f<<<4096, 256, 0, stream>>>(HPb, SRC, DST, NBR, CNT, x, H, Hb);

    // ---- GAT layer 1 ----
    k_gemm_mfma<<<dim3(4, 64), 256, 0, stream>>>(Hb, W1t, HPb, nullptr, nullptr, 4096, 256, 256, 1);
    k_scores<<<8192, 256, 0, stream>>>(HPb, as1, ad1, SRC, DST, 32);
    k_attn_small_f<<<4096, 256, 0, stream>>>(HPb, SRC, DST, NBR, CNT, H, H, Hb);

    // ---- GAT layer 2: scores from H, aggregate H, then GEMM with W2 (residual fused) ----
    k_scores2H<<<1024, 256, 0, stream>>>(H, WS2, WD2, SRC, DST);
    k_attn_Y<<<4096, 256, 0, stream>>>(Hb, SRC, DST, NBR, CNT, Ycat);
    k_gemm_mfma<<<dim3(4, 64), 256, 0, stream>>>(Ycat, W2t, G, nullptr, H, 4096, 256, 2048, 4);
    k_ln<<<1024, 256, 0, stream>>>(G, ln_g, ln_b, HLN, HLNb);

    // ---- FFN (bias+gelu and final residual+bias fused into GEMM epilogues) ----
    k_gemm_mfma<<<dim3(8, 64), 256, 0, stream>>>(HLNb, F1t, MIDb, ff_b1, nullptr, 4096, 512, 256, 2);
    k_gemm_mfma<<<dim3(4, 64), 256, 0, stream>>>(MIDb, F2t, (float*)d_out, ff_b2, HLN, 4096, 256, 512, 3);
}